// Round 5
// baseline (104.942 us; speedup 1.0000x reference)
//
#include <hip/hip_runtime.h>
#include <math.h>

// Problem constants (from reference setup_inputs)
constexpr int Bb = 128;   // batches
constexpr int Nn = 64;    // events per sequence
constexpr int Hh = 128;   // head events
constexpr int Gg = 4000;  // grid points
constexpr float  TOLf = 0.5f;
constexpr double RESd = 0.03;

constexpr int GBLK  = 16;           // grid blocks per batch, 256 pts each (R3-proven)
constexpr int NGRID = Bb * GBLK;    // 2048
constexpr int NBLK  = NGRID + Bb;   // + 128 event blocks = 2176
constexpr int TSTRIDE = 72;         // per-batch table stride in elements
constexpr int NACC = 16;            // spread accumulators (contention 2176/16 = 136)

// ---------------------------------------------------------------------------
// Branchless lower/upper bounds over sorted LDS arrays.
// ---------------------------------------------------------------------------
__device__ __forceinline__ int lb64(const float* __restrict__ a, float key) {
    int lo = (a[31] < key) ? 32 : 0;
    lo += (a[lo + 15] < key) ? 16 : 0;
    lo += (a[lo + 7]  < key) ? 8  : 0;
    lo += (a[lo + 3]  < key) ? 4  : 0;
    lo += (a[lo + 1]  < key) ? 2  : 0;
    lo += (a[lo]      < key) ? 1  : 0;
    lo += (a[lo]      < key) ? 1  : 0;   // resolves count==64
    return lo;
}
__device__ __forceinline__ int ub64(const float* __restrict__ a, float key) {
    int lo = (a[31] <= key) ? 32 : 0;
    lo += (a[lo + 15] <= key) ? 16 : 0;
    lo += (a[lo + 7]  <= key) ? 8  : 0;
    lo += (a[lo + 3]  <= key) ? 4  : 0;
    lo += (a[lo + 1]  <= key) ? 2  : 0;
    lo += (a[lo]      <= key) ? 1  : 0;
    lo += (a[lo]      <= key) ? 1  : 0;
    return lo;
}
__device__ __forceinline__ int lb128(const float* __restrict__ a, float key) {
    int lo = (a[63] < key) ? 64 : 0;
    lo += (a[lo + 31] < key) ? 32 : 0;
    lo += (a[lo + 15] < key) ? 16 : 0;
    lo += (a[lo + 7]  < key) ? 8  : 0;
    lo += (a[lo + 3]  < key) ? 4  : 0;
    lo += (a[lo + 1]  < key) ? 2  : 0;
    lo += (a[lo]      < key) ? 1  : 0;
    lo += (a[lo]      < key) ? 1  : 0;   // resolves count==128
    return lo;
}

// ---------------------------------------------------------------------------
// Kernel A: per-batch prefix tables (one wave per batch) + ws header init
//   (softmax weights, base, sE table, accumulators=0, ticket=0).
//   Same-stream ordering guarantees eval sees all of it. Graph-safe.
// ---------------------------------------------------------------------------
__global__ __launch_bounds__(64) void precompute_kernel(
    const float* __restrict__ times0, const int* __restrict__ states0,
    const float* __restrict__ times1, const int* __restrict__ states1,
    const float* __restrict__ base, const float* __restrict__ weights,
    double* __restrict__ Ps_all, double* __restrict__ Qs_all,
    double* __restrict__ SW_all, double* __restrict__ SWP_all,
    int* __restrict__ kT_all,
    double* __restrict__ hdr, double* __restrict__ sE_all,
    double* __restrict__ accArr, int* __restrict__ ticket)
{
    const int b = blockIdx.x;
    const int i = threadIdx.x;   // 0..63

    __shared__ float  t1s[Nn];
    __shared__ int    j0s[Nn];
    __shared__ double Ps_sh[Nn + 1];

    const float t0 = times0[b * Nn + i];
    const float t1 = times1[b * Nn + i];
    const int   s0 = states0[b * Nn + i];
    const int   s1 = states1[b * Nn + i];
    t1s[i] = t1;
    __syncthreads();

    int j0 = 0;
    #pragma unroll
    for (int j = 0; j < Nn; ++j)
        j0 += (t0 - t1s[j] >= -TOLf) ? 1 : 0;   // fp32 cmp, NOT(M) prefix length
    j0s[i] = j0;

    const double e0 = exp((double)t0);
    double vp = (s1 == 1) ? exp((double)t1) : 0.0;
    double vq = (s0 == 0) ? e0 : 0.0;
    const double W = (s0 == 1) ? e0 : 0.0;
    double vw = W;

    #pragma unroll
    for (int off = 1; off < 64; off <<= 1) {
        double op = __shfl_up(vp, off, 64);
        double oq = __shfl_up(vq, off, 64);
        double ow = __shfl_up(vw, off, 64);
        if (i >= off) { vp += op; vq += oq; vw += ow; }
    }
    Ps_sh[i + 1] = vp;
    if (i == 0) Ps_sh[0] = 0.0;
    __syncthreads();

    double vwp = W * Ps_sh[j0];
    #pragma unroll
    for (int off = 1; off < 64; off <<= 1) {
        double o = __shfl_up(vwp, off, 64);
        if (i >= off) vwp += o;
    }

    int kc = 0;
    #pragma unroll
    for (int j = 0; j < Nn; ++j)
        kc += (j0s[j] <= i) ? 1 : 0;

    double* Ps  = Ps_all  + b * TSTRIDE;
    double* Qs  = Qs_all  + b * TSTRIDE;
    double* SW  = SW_all  + b * TSTRIDE;
    double* SWP = SWP_all + b * TSTRIDE;
    int*    kT  = kT_all  + b * TSTRIDE;

    Ps[i + 1]  = vp;  Qs[i + 1]  = vq;
    SW[i + 1]  = vw;  SWP[i + 1] = vwp;
    kT[i] = kc;
    if (i == 0) {
        Ps[0] = 0.0; Qs[0] = 0.0; SW[0] = 0.0; SWP[0] = 0.0;
        kT[Nn] = Nn;
    }
    if (b == 0) {
        if (i < NACC) accArr[i] = 0.0;
        if (i < GBLK) {
            const double tb = (double)(i * 256) * 0.03;   // identical expr to eval's tbase
            sE_all[i] = exp(-tb);
        }
        if (i == 0) {
            const double w0 = (double)weights[0], w1 = (double)weights[1];
            const double mw = fmax(w0, w1);
            const double ew0 = exp(w0 - mw), ew1 = exp(w1 - mw);
            hdr[0] = ew0 / (ew0 + ew1);
            hdr[1] = ew1 / (ew0 + ew1);
            hdr[2] = (double)base[0];
            *ticket = 0;
        }
    }
}

// ---------------------------------------------------------------------------
// Kernel B: point evaluation + fence-free last-block finalize.
//   Block sums -> 16 spread device-scope fp64 atomics (coherence-point ops,
//   no L2-writeback fence). Ordering: consume atomic return (forces vmcnt
//   wait) before the ticket atomic. Last block atomically reads accumulators.
// ---------------------------------------------------------------------------
__global__ __launch_bounds__(256) void eval_kernel(
    const float* __restrict__ times0, const float* __restrict__ times1,
    const float* __restrict__ head_times, const int* __restrict__ head_states,
    const double* __restrict__ Ps_all, const double* __restrict__ Qs_all,
    const double* __restrict__ SW_all, const double* __restrict__ SWP_all,
    const int* __restrict__ kT_all,
    const double* __restrict__ hdr, const double* __restrict__ sE_all,
    double* __restrict__ accArr, int* __restrict__ ticket,
    float* __restrict__ out)
{
    __shared__ float  t0s[Nn], t1s[Nn];
    __shared__ float  hts[Hh];
    __shared__ int    hss[Hh];
    __shared__ double Ps[Nn + 1], Qs[Nn + 1], SW[Nn + 1], SWP[Nn + 1];
    __shared__ int    kT[Nn + 1];
    __shared__ double redsh[4];
    __shared__ int    amLast;

    const int tid = threadIdx.x;
    const bool isEvent = blockIdx.x >= (unsigned)NGRID;
    const int b     = isEvent ? (blockIdx.x - NGRID) : (blockIdx.x >> 4);
    const int gbase = isEvent ? 0 : ((blockIdx.x & 15) << 8);
    const double tbase = (double)gbase * 0.03;

    if (tid < Nn) {
        t0s[tid] = times0[b * Nn + tid];
        t1s[tid] = times1[b * Nn + tid];
    } else if (tid < 192) {
        const int k = tid - 64;
        hts[k] = head_times[b * Hh + k];
        hss[k] = head_states[b * Hh + k];
    } else {
        const double sE = isEvent ? 1.0 : sE_all[blockIdx.x & 15];
        int k = tid - 192;
        const int base_i = b * TSTRIDE;
        Ps[k]  = Ps_all [base_i + k] * sE;
        Qs[k]  = Qs_all [base_i + k] * sE;
        SW[k]  = SW_all [base_i + k] * sE;
        SWP[k] = SWP_all[base_i + k] * (sE * sE);
        kT[k]  = kT_all [base_i + k];
        if (tid == 192) {          // entry 64
            k = Nn;
            Ps[k]  = Ps_all [base_i + k] * sE;
            Qs[k]  = Qs_all [base_i + k] * sE;
            SW[k]  = SW_all [base_i + k] * sE;
            SWP[k] = SWP_all[base_i + k] * (sE * sE);
            kT[k]  = kT_all [base_i + k];
        }
    }
    __syncthreads();

    const double wn0 = hdr[0], wn1 = hdr[1], bse = hdr[2];

    double contrib = 0.0;

    if (isEvent) {
        if (tid >= 1 && tid < Hh) {
            const float tf = hts[tid];
            const float thr = tf - TOLf;
            const int c   = lb64(t1s, thr);
            const int c0  = lb64(t0s, thr);
            const int c1  = ub64(t0s, tf);
            const int cnt = lb128(hts, tf);

            const int m = min(c1, kT[c]);
            const double a  = Ps[c] * SW[m] - SWP[m];
            const double ed = exp(-(double)tf);
            const double f0 = a * ed * ed;
            const double f1 = Qs[c0] * ed;
            const int cur = hss[((unsigned)(cnt - 1)) & (unsigned)(Hh - 1)];
            const double eff = (cur == 0) ? 1.0 : -1.0;
            contrib = bse + eff * (wn0 * f0 - wn1 * f1);
        }
    } else {
        const int g = gbase + tid;
        if (g < Gg) {
            const float tf = (float)g * 0.03f;   // matches reference fp32 grid
            const float thr = tf - TOLf;
            const int c   = lb64(t1s, thr);
            const int c0  = lb64(t0s, thr);
            const int c1  = ub64(t0s, tf);
            const int cnt = lb128(hts, tf);

            const int m = min(c1, kT[c]);
            const double a = Ps[c] * SW[m] - SWP[m];     // scaled by e^{-2 t_base}
            const double dt = (double)tf - tbase;         // in [0, ~7.68]
            const float f0 = (float)a * __expf((float)(-2.0 * dt));
            const float f1 = (float)Qs[c0] * __expf((float)(-dt));
            const int cur = hss[((unsigned)(cnt - 1)) & (unsigned)(Hh - 1)];
            const float eff = (cur == 0) ? 1.0f : -1.0f;
            const float ll = (float)bse + eff * ((float)wn0 * f0 - (float)wn1 * f1);
            contrib = -RESd * (double)__expf(ll);
        }
    }

    // block reduction: wave shuffle, then 4-entry LDS
    double v = contrib;
    #pragma unroll
    for (int off = 32; off > 0; off >>= 1) v += __shfl_down(v, off, 64);
    if ((tid & 63) == 0) redsh[tid >> 6] = v;
    __syncthreads();

    if (tid == 0) {
        const double bsum = redsh[0] + redsh[1] + redsh[2] + redsh[3];
        // device-scope fp64 atomic: executes at coherence point, no fence needed
        double old = atomicAdd(&accArr[blockIdx.x & (NACC - 1)], bsum);
        // consume return value -> forces s_waitcnt vmcnt(0) (acc add globally
        // visible) before the ticket atomic below; "memory" pins ordering.
        __asm__ volatile("" :: "v"(old) : "memory");
        const int t = atomicAdd(ticket, 1);
        amLast = (t == NBLK - 1) ? 1 : 0;
    }
    __syncthreads();

    if (amLast) {
        // all 2176 acc-adds completed (each preceded its ticket increment);
        // atomic reads below observe the final values — no fence required.
        double s = (tid < NACC) ? atomicAdd(&accArr[tid], 0.0) : 0.0;
        if (tid < 64) {
            #pragma unroll
            for (int off = 8; off > 0; off >>= 1) s += __shfl_down(s, off, 64);
            if (tid == 0) out[0] = (float)s;
        }
    }
}

extern "C" void kernel_launch(void* const* d_in, const int* in_sizes, int n_in,
                              void* d_out, int out_size, void* d_ws, size_t ws_size,
                              hipStream_t stream) {
    const float* times0      = (const float*)d_in[0];
    const int*   states0     = (const int*)  d_in[1];
    const float* times1      = (const float*)d_in[2];
    const int*   states1     = (const int*)  d_in[3];
    const float* head_times  = (const float*)d_in[4];
    const int*   head_states = (const int*)  d_in[5];
    const float* base        = (const float*)d_in[6];
    const float* weights     = (const float*)d_in[7];

    double* Ps_all  = (double*)d_ws;
    double* Qs_all  = Ps_all  + Bb * TSTRIDE;
    double* SW_all  = Qs_all  + Bb * TSTRIDE;
    double* SWP_all = SW_all  + Bb * TSTRIDE;
    int*    kT_all  = (int*)(SWP_all + Bb * TSTRIDE);
    double* hdr     = (double*)(kT_all + Bb * TSTRIDE);   // 8B-aligned
    double* sE_all  = hdr + 8;       // 16 doubles
    double* accArr  = hdr + 24;      // 16 doubles
    int*    ticket  = (int*)(hdr + 40);

    precompute_kernel<<<Bb, 64, 0, stream>>>(times0, states0, times1, states1,
                                             base, weights,
                                             Ps_all, Qs_all, SW_all, SWP_all, kT_all,
                                             hdr, sE_all, accArr, ticket);
    eval_kernel<<<NBLK, 256, 0, stream>>>(times0, times1, head_times, head_states,
                                          Ps_all, Qs_all, SW_all, SWP_all, kT_all,
                                          hdr, sE_all, accArr, ticket,
                                          (float*)d_out);
}

// Round 6
// 78.665 us; speedup vs baseline: 1.3340x; 1.3340x over previous
//
#include <hip/hip_runtime.h>
#include <math.h>

// Problem constants (from reference setup_inputs)
constexpr int Bb = 128;   // batches
constexpr int Nn = 64;    // events per sequence
constexpr int Hh = 128;   // head events
constexpr int Gg = 4000;  // grid points
constexpr float  TOLf = 0.5f;
constexpr double RESd = 0.03;

constexpr int GBLK  = 16;           // grid blocks per batch, 256 pts each
constexpr int NGRID = Bb * GBLK;    // 2048
constexpr int NBLK  = NGRID + Bb;   // + 128 event blocks = 2176

// ---------------------------------------------------------------------------
// Branchless lower/upper bounds over sorted LDS arrays.
// ---------------------------------------------------------------------------
__device__ __forceinline__ int lb64(const float* __restrict__ a, float key) {
    int lo = (a[31] < key) ? 32 : 0;
    lo += (a[lo + 15] < key) ? 16 : 0;
    lo += (a[lo + 7]  < key) ? 8  : 0;
    lo += (a[lo + 3]  < key) ? 4  : 0;
    lo += (a[lo + 1]  < key) ? 2  : 0;
    lo += (a[lo]      < key) ? 1  : 0;
    lo += (a[lo]      < key) ? 1  : 0;   // resolves count==64
    return lo;
}
__device__ __forceinline__ int ub64(const float* __restrict__ a, float key) {
    int lo = (a[31] <= key) ? 32 : 0;
    lo += (a[lo + 15] <= key) ? 16 : 0;
    lo += (a[lo + 7]  <= key) ? 8  : 0;
    lo += (a[lo + 3]  <= key) ? 4  : 0;
    lo += (a[lo + 1]  <= key) ? 2  : 0;
    lo += (a[lo]      <= key) ? 1  : 0;
    lo += (a[lo]      <= key) ? 1  : 0;
    return lo;
}
__device__ __forceinline__ int lb128(const float* __restrict__ a, float key) {
    int lo = (a[63] < key) ? 64 : 0;
    lo += (a[lo + 31] < key) ? 32 : 0;
    lo += (a[lo + 15] < key) ? 16 : 0;
    lo += (a[lo + 7]  < key) ? 8  : 0;
    lo += (a[lo + 3]  < key) ? 4  : 0;
    lo += (a[lo + 1]  < key) ? 2  : 0;
    lo += (a[lo]      < key) ? 1  : 0;
    lo += (a[lo]      < key) ? 1  : 0;   // resolves count==128
    return lo;
}

// ---------------------------------------------------------------------------
// Fused kernel: per-block in-LDS table build (wave 0) + point evaluation.
//   NO global atomics, NO fences: block sums go to partials[] (plain store);
//   a separate tiny kernel reduces them. (R5 lesson: ~2k same-line device
//   atomics serialize at ~19 ns each = +40 us; plain stores are free.)
//   Grid blocks: tables scaled by e^{-t_base} during the scan so the
//   per-point tail is fp32 with native __expf. Event blocks: sE=1, fp64 tail.
// ---------------------------------------------------------------------------
__global__ __launch_bounds__(256) void eval_kernel(
    const float* __restrict__ times0, const int* __restrict__ states0,
    const float* __restrict__ times1, const int* __restrict__ states1,
    const float* __restrict__ head_times, const int* __restrict__ head_states,
    const float* __restrict__ base, const float* __restrict__ weights,
    double* __restrict__ partials)
{
    __shared__ float  t0s[Nn], t1s[Nn];
    __shared__ float  hts[Hh];
    __shared__ int    hss[Hh];
    __shared__ double Ps[Nn + 1], Qs[Nn + 1], SW[Nn + 1], SWP[Nn + 1];
    __shared__ int    kT[Nn + 1];
    __shared__ int    j0s[Nn];
    __shared__ double wsh[3];     // wn0, wn1, base
    __shared__ double redsh[4];

    const int tid = threadIdx.x;
    const bool isEvent = blockIdx.x >= (unsigned)NGRID;
    const int b     = isEvent ? (blockIdx.x - NGRID) : (blockIdx.x >> 4);
    const int gbase = isEvent ? 0 : ((blockIdx.x & 15) << 8);
    const double tbase = (double)gbase * 0.03;

    // ---- phase 1: coalesced input loads into LDS ----
    if (tid < Nn) {
        t0s[tid] = times0[b * Nn + tid];
    } else if (tid < 128) {
        t1s[tid - 64] = times1[b * Nn + (tid - 64)];
    } else {
        const int k = tid - 128;
        hts[k] = head_times[b * Hh + k];
        hss[k] = head_states[b * Hh + k];
    }
    __syncthreads();

    // ---- all threads: binary searches (need only t0s/t1s/hts) ----
    float tf = 0.0f;
    bool active = false;
    if (isEvent) {
        if (tid >= 1 && tid < Hh) { tf = hts[tid]; active = true; }
    } else {
        const int g = gbase + tid;
        if (g < Gg) { tf = (float)g * 0.03f; active = true; }  // ref fp32 grid
    }
    int c = 0, c0 = 0, c1 = 0, cnt = 0;
    if (active) {
        const float thr = tf - TOLf;
        c   = lb64(t1s, thr);
        c0  = lb64(t0s, thr);
        c1  = ub64(t0s, tf);
        cnt = lb128(hts, tf);
    }

    // ---- wave 0: build prefix tables in LDS (overlaps other waves' work) ----
    if (tid < Nn) {
        const int i = tid;
        const float t0 = t0s[i];
        const float t1 = t1s[i];
        const int   s0 = states0[b * Nn + i];
        const int   s1 = states1[b * Nn + i];

        int j0 = 0;
        #pragma unroll
        for (int j = 0; j < Nn; ++j)
            j0 += (t0 - t1s[j] >= -TOLf) ? 1 : 0;   // fp32 cmp, NOT(M) prefix len
        j0s[i] = j0;

        const double sE = isEvent ? 1.0 : exp(-tbase);
        const double e0 = exp((double)t0) * sE;
        double vp = (s1 == 1) ? exp((double)t1) * sE : 0.0;   // scaled p
        double vq = (s0 == 0) ? e0 : 0.0;                      // scaled q
        const double W = (s0 == 1) ? e0 : 0.0;                 // scaled W
        double vw = W;

        #pragma unroll
        for (int off = 1; off < 64; off <<= 1) {
            double op = __shfl_up(vp, off, 64);
            double oq = __shfl_up(vq, off, 64);
            double ow = __shfl_up(vw, off, 64);
            if (i >= off) { vp += op; vq += oq; vw += ow; }
        }
        Ps[i + 1] = vp;  Qs[i + 1] = vq;  SW[i + 1] = vw;
        if (i == 0) { Ps[0] = 0.0; Qs[0] = 0.0; SW[0] = 0.0; SWP[0] = 0.0; kT[Nn] = Nn; }

        // W'*Ps'[j0] = (W*sE)*(Ps[j0]*sE) -> SWP scaled by sE^2, as required.
        // Same-wave LDS RAW (Ps writes above -> read here): lockstep + lgkmcnt.
        double vwp = W * Ps[j0];
        #pragma unroll
        for (int off = 1; off < 64; off <<= 1) {
            double o = __shfl_up(vwp, off, 64);
            if (i >= off) vwp += o;
        }
        SWP[i + 1] = vwp;

        int kc = 0;
        #pragma unroll
        for (int j = 0; j < Nn; ++j)
            kc += (j0s[j] <= i) ? 1 : 0;
        kT[i] = kc;
    } else if (tid == 64) {
        const double w0 = (double)weights[0], w1 = (double)weights[1];
        const double mw = fmax(w0, w1);
        const double ew0 = exp(w0 - mw), ew1 = exp(w1 - mw);
        wsh[0] = ew0 / (ew0 + ew1);
        wsh[1] = ew1 / (ew0 + ew1);
        wsh[2] = (double)base[0];
    }
    __syncthreads();

    // ---- tail: intensity from tables ----
    double contrib = 0.0;
    if (active) {
        const int m = min(c1, kT[c]);
        const int cur = hss[((unsigned)(cnt - 1)) & (unsigned)(Hh - 1)];
        if (isEvent) {
            const double a  = Ps[c] * SW[m] - SWP[m];
            const double ed = exp(-(double)tf);
            const double f0 = a * ed * ed;
            const double f1 = Qs[c0] * ed;
            const double eff = (cur == 0) ? 1.0 : -1.0;
            contrib = wsh[2] + eff * (wsh[0] * f0 - wsh[1] * f1);
        } else {
            const double a = Ps[c] * SW[m] - SWP[m];     // scaled by e^{-2 t_base}
            const double dt = (double)tf - tbase;         // in [0, ~7.68]
            const float f0 = (float)a * __expf((float)(-2.0 * dt));
            const float f1 = (float)Qs[c0] * __expf((float)(-dt));
            const float eff = (cur == 0) ? 1.0f : -1.0f;
            const float ll = (float)wsh[2] + eff * ((float)wsh[0] * f0 - (float)wsh[1] * f1);
            contrib = -RESd * (double)__expf(ll);
        }
    }

    // ---- block reduction -> plain global store (no atomics, no fence) ----
    double v = contrib;
    #pragma unroll
    for (int off = 32; off > 0; off >>= 1) v += __shfl_down(v, off, 64);
    if ((tid & 63) == 0) redsh[tid >> 6] = v;
    __syncthreads();
    if (tid == 0) partials[blockIdx.x] = redsh[0] + redsh[1] + redsh[2] + redsh[3];
}

// ---------------------------------------------------------------------------
// Reduce partials -> out (separate dispatch; stream order guarantees data).
// ---------------------------------------------------------------------------
__global__ __launch_bounds__(256) void finalize_kernel(
    const double* __restrict__ partials, float* __restrict__ out)
{
    __shared__ double redsh[4];
    const int tid = threadIdx.x;
    double v = 0.0;
    for (int i = tid; i < NBLK; i += 256) v += partials[i];
    #pragma unroll
    for (int off = 32; off > 0; off >>= 1) v += __shfl_down(v, off, 64);
    if ((tid & 63) == 0) redsh[tid >> 6] = v;
    __syncthreads();
    if (tid == 0) out[0] = (float)(redsh[0] + redsh[1] + redsh[2] + redsh[3]);
}

extern "C" void kernel_launch(void* const* d_in, const int* in_sizes, int n_in,
                              void* d_out, int out_size, void* d_ws, size_t ws_size,
                              hipStream_t stream) {
    const float* times0      = (const float*)d_in[0];
    const int*   states0     = (const int*)  d_in[1];
    const float* times1      = (const float*)d_in[2];
    const int*   states1     = (const int*)  d_in[3];
    const float* head_times  = (const float*)d_in[4];
    const int*   head_states = (const int*)  d_in[5];
    const float* base        = (const float*)d_in[6];
    const float* weights     = (const float*)d_in[7];

    double* partials = (double*)d_ws;   // NBLK doubles

    eval_kernel<<<NBLK, 256, 0, stream>>>(times0, states0, times1, states1,
                                          head_times, head_states, base, weights,
                                          partials);
    finalize_kernel<<<1, 256, 0, stream>>>(partials, (float*)d_out);
}